// Round 11
// baseline (137.351 us; speedup 1.0000x reference)
//
#include <hip/hip_runtime.h>
#include <math.h>

#define B_ 8
#define N_ 128
#define L_ 30
#define D_ 256
#define NEGV -1000000000.0f
#define SCALE 0.0625f   // 1/sqrt(256)

// ---- Kernel 1: k = f_w@Wk^T + bk ; k2 = k@Wq ; s_l = bq.k[l]  (60 blocks x 4 rows) ----
__global__ __launch_bounds__(256) void kk2s(const float* __restrict__ f_w,
    const float* __restrict__ Wk, const float* __restrict__ bk,
    const float* __restrict__ Wq, const float* __restrict__ bq,
    float* __restrict__ k2mat, float* __restrict__ sv) {
  int row0 = blockIdx.x * 4;      // 240 rows total
  int t = threadIdx.x, wave = t >> 6, lane = t & 63;

  __shared__ float wt[32][257];   // transposed Wk chunk: wt[dd][c] = Wk[c][d0+dd]
  __shared__ float fwl[4][257];
  __shared__ float kl[4][257];
  __shared__ float red[4][4];

#pragma unroll
  for (int r = 0; r < 4; ++r)
    fwl[r][t] = f_w[(size_t)(row0 + r) * D_ + t];

  // ---- stage 1: k[r][c] = sum_d fwl[r][d] * Wk[c][d]   (thread t = c)
  float acc[4] = {0.f, 0.f, 0.f, 0.f};
  for (int chunk = 0; chunk < 8; ++chunk) {
    int d0 = chunk * 32;
    __syncthreads();
#pragma unroll
    for (int j = 0; j < 32; ++j) {
      int linear = j * 256 + t;
      int c = linear >> 5, dd = linear & 31;
      wt[dd][c] = Wk[(size_t)c * D_ + d0 + dd];   // coalesced-ish 128B runs
    }
    __syncthreads();
#pragma unroll
    for (int dd = 0; dd < 32; ++dd) {
      float wv = wt[dd][t];                        // CF: consecutive t -> consecutive banks
#pragma unroll
      for (int r = 0; r < 4; ++r)
        acc[r] += fwl[r][d0 + dd] * wv;            // LDS broadcast
    }
  }
  __syncthreads();
  float bkt = bk[t];
#pragma unroll
  for (int r = 0; r < 4; ++r) kl[r][t] = acc[r] + bkt;
  __syncthreads();

  // ---- stage 2: k2[r][j] = sum_i kl[r][i] * Wq[i][j]   (thread t = j, Wq rows coalesced)
  float acc2[4] = {0.f, 0.f, 0.f, 0.f};
  for (int i4 = 0; i4 < 64; ++i4) {
    float w0 = Wq[(size_t)(4 * i4 + 0) * D_ + t];
    float w1 = Wq[(size_t)(4 * i4 + 1) * D_ + t];
    float w2 = Wq[(size_t)(4 * i4 + 2) * D_ + t];
    float w3 = Wq[(size_t)(4 * i4 + 3) * D_ + t];
#pragma unroll
    for (int r = 0; r < 4; ++r) {
      float4 kv = ((const float4*)kl[r])[i4];      // b128 LDS, CF broadcast
      acc2[r] += kv.x * w0 + kv.y * w1 + kv.z * w2 + kv.w * w3;
    }
  }
#pragma unroll
  for (int r = 0; r < 4; ++r)
    k2mat[(size_t)(row0 + r) * D_ + t] = acc2[r];

  // ---- s_l = sum_i bq[i] * k[l][i]
  float bqt = bq[t];
#pragma unroll
  for (int r = 0; r < 4; ++r) {
    float v = bqt * kl[r][t];
#pragma unroll
    for (int off = 32; off >= 1; off >>= 1) v += __shfl_xor(v, off);
    if (lane == 0) red[r][wave] = v;
  }
  __syncthreads();
  if (t < 4)
    sv[row0 + t] = red[t][0] + red[t][1] + red[t][2] + red[t][3];
}

// ---- Kernel 2: aw[n,l]=(f_b[n].k2[l]+s_l)*scale -> softmax(L) -> f_bq ----
__global__ __launch_bounds__(256) void aw_fbq(const float* __restrict__ f_b,
    const float* __restrict__ f_w, const float* __restrict__ f_s,
    const float* __restrict__ qmask, const float* __restrict__ lmask,
    const float* __restrict__ k2mat, const float* __restrict__ sv,
    float* __restrict__ fbq) {
  int blk = blockIdx.x;           // 128 blocks
  int b = blk >> 4, n0 = (blk & 15) * 8;
  int t = threadIdx.x;

  __shared__ float k2l[L_][260];
  __shared__ float fbl[8][260];
  __shared__ float awl[8][32];
  __shared__ float slds[32];

  for (int r = 0; r < 8; ++r)
    fbl[r][t] = f_b[(size_t)(b * N_ + n0 + r) * D_ + t];
  for (int l = 0; l < L_; ++l)
    k2l[l][t] = k2mat[(size_t)(b * L_ + l) * D_ + t];
  if (t < L_) slds[t] = sv[b * L_ + t];
  __syncthreads();

  if (t < 240) {
    int r = t / 30, l = t % 30;
    const float4* fr = (const float4*)fbl[r];
    const float4* kr = (const float4*)k2l[l];
    float acc = 0.f;
#pragma unroll 8
    for (int j = 0; j < 64; ++j) {
      float4 a4 = fr[j], b4 = kr[j];
      acc += a4.x*b4.x + a4.y*b4.y + a4.z*b4.z + a4.w*b4.w;
    }
    float aw = (acc + slds[l]) * SCALE;
    float qm = qmask[b * L_ + l];
    awl[r][l] = (qm == 0.f) ? NEGV : aw * qm;
  }
  __syncthreads();

  if (t < 8) {
    float mx = -1e30f;
    for (int l = 0; l < L_; ++l) mx = fmaxf(mx, awl[t][l]);
    float s = 0.f;
    for (int l = 0; l < L_; ++l) { float e = __expf(awl[t][l] - mx); awl[t][l] = e; s += e; }
    float inv = 1.f / s;
    for (int l = 0; l < L_; ++l) awl[t][l] *= inv;
  }
  __syncthreads();

  for (int l = 0; l < L_; ++l)            // reuse k2l for f_w rows
    k2l[l][t] = f_w[(size_t)(b * L_ + l) * D_ + t];
  __syncthreads();

  float fsd = f_s[b * D_ + t];
  for (int r = 0; r < 8; ++r) {
    float facc = 0.f;
#pragma unroll
    for (int l = 0; l < L_; ++l) facc += awl[r][l] * k2l[l][t];
    float lm = lmask[b * N_ + n0 + r];
    fbq[(size_t)(b * N_ + n0 + r) * D_ + t] = fbl[r][t] * (facc * lm + fsd);
  }
}

// ---- Kernel 3 (measured 35.6us): A-row softmax + f_bb fold + sigmoid f_m stream ----
// out[n,:] = f_b[n] + sum_m A'[n,m]*(lmn*f_b[m] + sigmoid(fm*fs)*fm)
__global__ __launch_bounds__(256) void fused_stream(const float* __restrict__ f_b,
    const float* __restrict__ f_m, const float* __restrict__ f_s,
    const float* __restrict__ lmask, const float* __restrict__ fbq,
    float* __restrict__ out) {
  int bn = blockIdx.x, b = bn >> 7, n = bn & 127;
  int t = threadIdx.x, w = t >> 6, lane = t & 63;

  __shared__ float part[4][32][65];   // 33.3 KB
  __shared__ float a_lds[N_];
  __shared__ float sm[8];
  __shared__ float4 red[3][64];       // 3 KB

  const float4* fmb = (const float4*)(f_m + (size_t)bn * N_ * D_);
  const float4* fbb = (const float4*)(f_b + (size_t)b * N_ * D_);
  int m0 = w * 32;                    // wave's m-range [m0, m0+32)

  // ---- preload f_m batch0 (rows m0..m0+7) — in flight during all of phase A
  float4 pA[8], pB[8];
#pragma unroll
  for (int i = 0; i < 8; ++i) pA[i] = fmb[(size_t)(m0 + i) * 64 + lane];
  __builtin_amdgcn_sched_barrier(0);

  // ---- Phase A: raw A dots (coalesced 1KB row loads, LDS transpose-reduce)
  float4 qv = ((const float4*)(fbq + (size_t)bn * D_))[lane];
#pragma unroll 8
  for (int i = 0; i < 32; ++i) {
    float4 v = ((const float4*)(fbq + (size_t)(b * N_ + m0 + i) * D_))[lane];
    part[w][i][lane] = v.x*qv.x + v.y*qv.y + v.z*qv.z + v.w*qv.w;
  }
  __syncthreads();
  float s = 0.f;
#pragma unroll
  for (int j = 0; j < 32; ++j)
    s += part[w][lane & 31][(lane >> 5) * 32 + j];   // CF: banks (lane&31 + j)%32
  s += __shfl_xor(s, 32);
  if (lane < 32) a_lds[m0 + (lane & 31)] = s;
  __syncthreads();

  // ---- softmax over 128 (threads 0..127), masked, * lmask[n]
  float lmn = lmask[b * N_ + n];
  float e = 0.f;
  if (t < N_) {
    float lm = lmask[b * N_ + t];
    float v = (lm == 0.f) ? NEGV : a_lds[t] * SCALE * lm;
    float mx = v;
#pragma unroll
    for (int off = 32; off >= 1; off >>= 1) mx = fmaxf(mx, __shfl_xor(mx, off));
    if (lane == 0) sm[w] = mx;
  }
  __syncthreads();
  if (t < N_) {
    float lm = lmask[b * N_ + t];
    float v = (lm == 0.f) ? NEGV : a_lds[t] * SCALE * lm;
    float gmax = fmaxf(sm[0], sm[1]);
    e = __expf(v - gmax);
    float ss = e;
#pragma unroll
    for (int off = 32; off >= 1; off >>= 1) ss += __shfl_xor(ss, off);
    if (lane == 0) sm[4 + w] = ss;
  }
  __syncthreads();
  if (t < N_) {
    float tot = sm[4] + sm[5];
    a_lds[t] = e * (lmn / tot);
  }
  __syncthreads();

  // ---- Phase B: double-buffered register stream of f_m + L2-hot f_b fold
  float4 fs4 = ((const float4*)(f_s + (size_t)b * D_))[lane];
  const float CLOG = -1.44269504088896f;  // -log2(e)
  float4 cs;
  cs.x = fs4.x * CLOG; cs.y = fs4.y * CLOG;
  cs.z = fs4.z * CLOG; cs.w = fs4.w * CLOG;
  float4 acc = make_float4(0.f, 0.f, 0.f, 0.f);

  auto compute8 = [&](float4 (&P)[8], int mbase) {
#pragma unroll
    for (int i = 0; i < 8; ++i) {
      int m = mbase + i;
      float a = a_lds[m];                               // LDS broadcast
      float4 fb4 = fbb[(size_t)m * 64 + lane];          // L2-hot
      float4 fm4 = P[i];
      float gx = __builtin_amdgcn_rcpf(1.f + __builtin_amdgcn_exp2f(fm4.x * cs.x));
      float gy = __builtin_amdgcn_rcpf(1.f + __builtin_amdgcn_exp2f(fm4.y * cs.y));
      float gz = __builtin_amdgcn_rcpf(1.f + __builtin_amdgcn_exp2f(fm4.z * cs.z));
      float gw = __builtin_amdgcn_rcpf(1.f + __builtin_amdgcn_exp2f(fm4.w * cs.w));
      acc.x += a * (lmn * fb4.x + gx * fm4.x);
      acc.y += a * (lmn * fb4.y + gy * fm4.y);
      acc.z += a * (lmn * fb4.z + gz * fm4.z);
      acc.w += a * (lmn * fb4.w + gw * fm4.w);
    }
  };

#pragma unroll
  for (int i = 0; i < 8; ++i) pB[i] = fmb[(size_t)(m0 + 8 + i) * 64 + lane];
  compute8(pA, m0);
#pragma unroll
  for (int i = 0; i < 8; ++i) pA[i] = fmb[(size_t)(m0 + 16 + i) * 64 + lane];
  compute8(pB, m0 + 8);
#pragma unroll
  for (int i = 0; i < 8; ++i) pB[i] = fmb[(size_t)(m0 + 24 + i) * 64 + lane];
  compute8(pA, m0 + 16);
  compute8(pB, m0 + 24);

  // ---- epilogue: cross-wave reduce + residual + store
  if (w > 0) red[w - 1][lane] = acc;
  __syncthreads();
  if (w == 0) {
#pragma unroll
    for (int j = 0; j < 3; ++j) {
      float4 r4 = red[j][lane];
      acc.x += r4.x; acc.y += r4.y; acc.z += r4.z; acc.w += r4.w;
    }
    float4 fbn = fbb[(size_t)n * 64 + lane];
    float4 o;
    o.x = fbn.x + acc.x;
    o.y = fbn.y + acc.y;
    o.z = fbn.z + acc.z;
    o.w = fbn.w + acc.w;
    ((float4*)out)[(size_t)bn * 64 + lane] = o;
  }
}

extern "C" void kernel_launch(void* const* d_in, const int* in_sizes, int n_in,
                              void* d_out, int out_size, void* d_ws, size_t ws_size,
                              hipStream_t stream) {
  const float* f_b   = (const float*)d_in[0];
  const float* f_w   = (const float*)d_in[1];
  const float* f_s   = (const float*)d_in[2];
  const float* f_m   = (const float*)d_in[3];
  const float* qmask = (const float*)d_in[4];
  const float* lmask = (const float*)d_in[5];
  const float* Wq    = (const float*)d_in[6];
  const float* bq    = (const float*)d_in[7];
  const float* Wk    = (const float*)d_in[8];
  const float* bk    = (const float*)d_in[9];
  float* out = (float*)d_out;

  float* ws    = (float*)d_ws;
  float* k2mat = ws;                        // 61440  (pad to 65536)
  float* sv    = ws + 65536;                // 240    (pad to 1024)
  float* fbq   = ws + 131072;               // 262144

  hipLaunchKernelGGL(kk2s, dim3(60), dim3(256), 0, stream,
                     f_w, Wk, bk, Wq, bq, k2mat, sv);
  hipLaunchKernelGGL(aw_fbq, dim3(B_ * N_ / 8), dim3(256), 0, stream,
                     f_b, f_w, f_s, qmask, lmask, k2mat, sv, fbq);
  hipLaunchKernelGGL(fused_stream, dim3(B_ * N_), dim3(256), 0, stream,
                     f_b, f_m, f_s, lmask, fbq, out);
}

// Round 12
// 88.159 us; speedup vs baseline: 1.5580x; 1.5580x over previous
//
#include <hip/hip_runtime.h>
#include <math.h>

#define B_ 8
#define N_ 128
#define L_ 30
#define D_ 256
#define NEGV -1000000000.0f
#define SCALE 0.0625f   // 1/sqrt(256)

// ---- Kernel 1 (R10-proven): k = f_w@Wk^T + bk ; k2 = k@Wq ; s_l = bq.k[l] ----
// 60 blocks x 4 k-rows. Coalesced float4 Wk-row loads + LDS transpose-reduce.
__global__ __launch_bounds__(256) void kk2s(const float* __restrict__ f_w,
    const float* __restrict__ Wk, const float* __restrict__ bk,
    const float* __restrict__ Wq, const float* __restrict__ bq,
    float* __restrict__ k2mat, float* __restrict__ sv) {
  int row0 = blockIdx.x * 4;      // 240 rows total
  int t = threadIdx.x, wave = t >> 6, lane = t & 63;
  __shared__ float part[4][16][65];
  __shared__ float klds[4][D_];   // 256 stride: float4-aligned rows

  float4 x4[4];
#pragma unroll
  for (int r = 0; r < 4; ++r)
    x4[r] = ((const float4*)(f_w + (size_t)(row0 + r) * D_))[lane];

  // stage 1: k rows -> klds (coalesced Wk rows + LDS transpose reduce)
  for (int g = 0; g < 4; ++g) {
    int dbase = wave * 64 + g * 16;
#pragma unroll
    for (int r = 0; r < 4; ++r) {
#pragma unroll
      for (int i = 0; i < 16; ++i) {
        float4 w4 = ((const float4*)(Wk + (size_t)(dbase + i) * D_))[lane];
        part[wave][i][lane] = w4.x*x4[r].x + w4.y*x4[r].y + w4.z*x4[r].z + w4.w*x4[r].w;
      }
      float s = 0.f;
#pragma unroll
      for (int j = 0; j < 16; ++j)
        s += part[wave][lane & 15][(lane >> 4) * 16 + j];
      s += __shfl_xor(s, 16);
      s += __shfl_xor(s, 32);
      if (lane < 16) klds[r][dbase + lane] = s + bk[dbase + lane];
    }
  }
  __syncthreads();

  // stage 2: k2[r][t] = sum_d klds[r][d] * Wq[d][t]   (coalesced over t)
  float acc[4] = {0.f, 0.f, 0.f, 0.f};
  for (int d4 = 0; d4 < 64; ++d4) {
    float w0 = Wq[(size_t)(4 * d4 + 0) * D_ + t];
    float w1 = Wq[(size_t)(4 * d4 + 1) * D_ + t];
    float w2 = Wq[(size_t)(4 * d4 + 2) * D_ + t];
    float w3 = Wq[(size_t)(4 * d4 + 3) * D_ + t];
#pragma unroll
    for (int r = 0; r < 4; ++r) {
      float4 kv = ((const float4*)klds[r])[d4];   // aligned LDS broadcast
      acc[r] += kv.x * w0 + kv.y * w1 + kv.z * w2 + kv.w * w3;
    }
  }
#pragma unroll
  for (int r = 0; r < 4; ++r)
    k2mat[(size_t)(row0 + r) * D_ + t] = acc[r];

  // s_l = sum_d bq[d]*k[l][d]
  float bqt = bq[t];
#pragma unroll
  for (int r = 0; r < 4; ++r) {
    float v = bqt * klds[r][t];
#pragma unroll
    for (int off = 32; off >= 1; off >>= 1) v += __shfl_xor(v, off);
    if (lane == 0) part[0][r][wave] = v;
  }
  __syncthreads();
  if (t < 4)
    sv[row0 + t] = part[0][t][0] + part[0][t][1] + part[0][t][2] + part[0][t][3];
}

// ---- Kernel 2 (proven R10/R11): aw[n,l]=(f_b[n].k2[l]+s_l)*scale -> softmax -> f_bq ----
__global__ __launch_bounds__(256) void aw_fbq(const float* __restrict__ f_b,
    const float* __restrict__ f_w, const float* __restrict__ f_s,
    const float* __restrict__ qmask, const float* __restrict__ lmask,
    const float* __restrict__ k2mat, const float* __restrict__ sv,
    float* __restrict__ fbq) {
  int blk = blockIdx.x;           // 128 blocks
  int b = blk >> 4, n0 = (blk & 15) * 8;
  int t = threadIdx.x;

  __shared__ float k2l[L_][260];
  __shared__ float fbl[8][260];
  __shared__ float awl[8][32];
  __shared__ float slds[32];

  for (int r = 0; r < 8; ++r)
    fbl[r][t] = f_b[(size_t)(b * N_ + n0 + r) * D_ + t];
  for (int l = 0; l < L_; ++l)
    k2l[l][t] = k2mat[(size_t)(b * L_ + l) * D_ + t];
  if (t < L_) slds[t] = sv[b * L_ + t];
  __syncthreads();

  if (t < 240) {
    int r = t / 30, l = t % 30;
    const float* fr = fbl[r];
    const float* kr = k2l[l];
    float acc = 0.f;
#pragma unroll 8
    for (int j = 0; j < D_; ++j) acc += fr[j] * kr[j];
    float aw = (acc + slds[l]) * SCALE;
    float qm = qmask[b * L_ + l];
    awl[r][l] = (qm == 0.f) ? NEGV : aw * qm;
  }
  __syncthreads();

  if (t < 8) {
    float mx = -1e30f;
    for (int l = 0; l < L_; ++l) mx = fmaxf(mx, awl[t][l]);
    float s = 0.f;
    for (int l = 0; l < L_; ++l) { float e = __expf(awl[t][l] - mx); awl[t][l] = e; s += e; }
    float inv = 1.f / s;
    for (int l = 0; l < L_; ++l) awl[t][l] *= inv;
  }
  __syncthreads();

  for (int l = 0; l < L_; ++l)            // reuse k2l for f_w rows
    k2l[l][t] = f_w[(size_t)(b * L_ + l) * D_ + t];
  __syncthreads();

  float fsd = f_s[b * D_ + t];
  for (int r = 0; r < 8; ++r) {
    float facc = 0.f;
#pragma unroll
    for (int l = 0; l < L_; ++l) facc += awl[r][l] * k2l[l][t];
    float lm = lmask[b * N_ + n0 + r];
    fbq[(size_t)(b * N_ + n0 + r) * D_ + t] = fbl[r][t] * (facc * lm + fsd);
  }
}

// ---- Kernel 3 (measured 35.6us, R5/R9): A-row softmax + f_bb fold + sigmoid f_m stream ----
// out[n,:] = f_b[n] + sum_m A'[n,m]*(lmn*f_b[m] + sigmoid(fm*fs)*fm)
__global__ __launch_bounds__(256) void fused_stream(const float* __restrict__ f_b,
    const float* __restrict__ f_m, const float* __restrict__ f_s,
    const float* __restrict__ lmask, const float* __restrict__ fbq,
    float* __restrict__ out) {
  int bn = blockIdx.x, b = bn >> 7, n = bn & 127;
  int t = threadIdx.x, w = t >> 6, lane = t & 63;

  __shared__ float part[4][32][65];   // 33.3 KB
  __shared__ float a_lds[N_];
  __shared__ float sm[8];
  __shared__ float4 red[3][64];       // 3 KB

  const float4* fmb = (const float4*)(f_m + (size_t)bn * N_ * D_);
  const float4* fbb = (const float4*)(f_b + (size_t)b * N_ * D_);
  int m0 = w * 32;                    // wave's m-range [m0, m0+32)

  // ---- preload f_m batch0 (rows m0..m0+7) — in flight during all of phase A
  float4 pA[8], pB[8];
#pragma unroll
  for (int i = 0; i < 8; ++i) pA[i] = fmb[(size_t)(m0 + i) * 64 + lane];
  __builtin_amdgcn_sched_barrier(0);

  // ---- Phase A: raw A dots (coalesced 1KB row loads, LDS transpose-reduce)
  float4 qv = ((const float4*)(fbq + (size_t)bn * D_))[lane];
#pragma unroll 8
  for (int i = 0; i < 32; ++i) {
    float4 v = ((const float4*)(fbq + (size_t)(b * N_ + m0 + i) * D_))[lane];
    part[w][i][lane] = v.x*qv.x + v.y*qv.y + v.z*qv.z + v.w*qv.w;
  }
  __syncthreads();
  float s = 0.f;
#pragma unroll
  for (int j = 0; j < 32; ++j)
    s += part[w][lane & 31][(lane >> 5) * 32 + j];   // CF: banks (lane&31 + j)%32
  s += __shfl_xor(s, 32);
  if (lane < 32) a_lds[m0 + (lane & 31)] = s;
  __syncthreads();

  // ---- softmax over 128 (threads 0..127), masked, * lmask[n]
  float lmn = lmask[b * N_ + n];
  float e = 0.f;
  if (t < N_) {
    float lm = lmask[b * N_ + t];
    float v = (lm == 0.f) ? NEGV : a_lds[t] * SCALE * lm;
    float mx = v;
#pragma unroll
    for (int off = 32; off >= 1; off >>= 1) mx = fmaxf(mx, __shfl_xor(mx, off));
    if (lane == 0) sm[w] = mx;
  }
  __syncthreads();
  if (t < N_) {
    float lm = lmask[b * N_ + t];
    float v = (lm == 0.f) ? NEGV : a_lds[t] * SCALE * lm;
    float gmax = fmaxf(sm[0], sm[1]);
    e = __expf(v - gmax);
    float ss = e;
#pragma unroll
    for (int off = 32; off >= 1; off >>= 1) ss += __shfl_xor(ss, off);
    if (lane == 0) sm[4 + w] = ss;
  }
  __syncthreads();
  if (t < N_) {
    float tot = sm[4] + sm[5];
    a_lds[t] = e * (lmn / tot);
  }
  __syncthreads();

  // ---- Phase B: double-buffered register stream of f_m + L2-hot f_b fold
  float4 fs4 = ((const float4*)(f_s + (size_t)b * D_))[lane];
  const float CLOG = -1.44269504088896f;  // -log2(e)
  float4 cs;
  cs.x = fs4.x * CLOG; cs.y = fs4.y * CLOG;
  cs.z = fs4.z * CLOG; cs.w = fs4.w * CLOG;
  float4 acc = make_float4(0.f, 0.f, 0.f, 0.f);

  auto compute8 = [&](float4 (&P)[8], int mbase) {
#pragma unroll
    for (int i = 0; i < 8; ++i) {
      int m = mbase + i;
      float a = a_lds[m];                               // LDS broadcast
      float4 fb4 = fbb[(size_t)m * 64 + lane];          // L2-hot
      float4 fm4 = P[i];
      float gx = __builtin_amdgcn_rcpf(1.f + __builtin_amdgcn_exp2f(fm4.x * cs.x));
      float gy = __builtin_amdgcn_rcpf(1.f + __builtin_amdgcn_exp2f(fm4.y * cs.y));
      float gz = __builtin_amdgcn_rcpf(1.f + __builtin_amdgcn_exp2f(fm4.z * cs.z));
      float gw = __builtin_amdgcn_rcpf(1.f + __builtin_amdgcn_exp2f(fm4.w * cs.w));
      acc.x += a * (lmn * fb4.x + gx * fm4.x);
      acc.y += a * (lmn * fb4.y + gy * fm4.y);
      acc.z += a * (lmn * fb4.z + gz * fm4.z);
      acc.w += a * (lmn * fb4.w + gw * fm4.w);
    }
  };

#pragma unroll
  for (int i = 0; i < 8; ++i) pB[i] = fmb[(size_t)(m0 + 8 + i) * 64 + lane];
  compute8(pA, m0);
#pragma unroll
  for (int i = 0; i < 8; ++i) pA[i] = fmb[(size_t)(m0 + 16 + i) * 64 + lane];
  compute8(pB, m0 + 8);
#pragma unroll
  for (int i = 0; i < 8; ++i) pB[i] = fmb[(size_t)(m0 + 24 + i) * 64 + lane];
  compute8(pA, m0 + 16);
  compute8(pB, m0 + 24);

  // ---- epilogue: cross-wave reduce + residual + store
  if (w > 0) red[w - 1][lane] = acc;
  __syncthreads();
  if (w == 0) {
#pragma unroll
    for (int j = 0; j < 3; ++j) {
      float4 r4 = red[j][lane];
      acc.x += r4.x; acc.y += r4.y; acc.z += r4.z; acc.w += r4.w;
    }
    float4 fbn = fbb[(size_t)n * 64 + lane];
    float4 o;
    o.x = fbn.x + acc.x;
    o.y = fbn.y + acc.y;
    o.z = fbn.z + acc.z;
    o.w = fbn.w + acc.w;
    ((float4*)out)[(size_t)bn * 64 + lane] = o;
  }
}

extern "C" void kernel_launch(void* const* d_in, const int* in_sizes, int n_in,
                              void* d_out, int out_size, void* d_ws, size_t ws_size,
                              hipStream_t stream) {
  const float* f_b   = (const float*)d_in[0];
  const float* f_w   = (const float*)d_in[1];
  const float* f_s   = (const float*)d_in[2];
  const float* f_m   = (const float*)d_in[3];
  const float* qmask = (const float*)d_in[4];
  const float* lmask = (const float*)d_in[5];
  const float* Wq    = (const float*)d_in[6];
  const float* bq    = (const float*)d_in[7];
  const float* Wk    = (const float*)d_in[8];
  const float* bk    = (const float*)d_in[9];
  float* out = (float*)d_out;

  float* ws    = (float*)d_ws;
  float* k2mat = ws;                        // 61440  (pad to 65536)
  float* sv    = ws + 65536;                // 240    (pad to 1024)
  float* fbq   = ws + 131072;               // 262144

  hipLaunchKernelGGL(kk2s, dim3(60), dim3(256), 0, stream,
                     f_w, Wk, bk, Wq, bq, k2mat, sv);
  hipLaunchKernelGGL(aw_fbq, dim3(B_ * N_ / 8), dim3(256), 0, stream,
                     f_b, f_w, f_s, qmask, lmask, k2mat, sv, fbq);
  hipLaunchKernelGGL(fused_stream, dim3(B_ * N_), dim3(256), 0, stream,
                     f_b, f_m, f_s, lmask, fbq, out);
}

// Round 13
// 64.147 us; speedup vs baseline: 2.1412x; 1.3743x over previous
//
#include <hip/hip_runtime.h>
#include <math.h>

#define B_ 8
#define N_ 128
#define L_ 30
#define D_ 256
#define NEGV -1000000000.0f
#define SCALE 0.0625f   // 1/sqrt(256)

// ---- K0: 257 blocks. blocks 0..255 (d=blk): W2[d][t]=sum_c Wk[c][d]*Wq[c][t],
//      wbq[d]=sum_c bq[c]*Wk[c][d]. block 256: bb[t]=sum_c bk[c]*Wq[c][t], c0=bq.bk
__global__ __launch_bounds__(256) void w2prep(const float* __restrict__ Wk,
    const float* __restrict__ Wq, const float* __restrict__ bq,
    const float* __restrict__ bk, float* __restrict__ W2,
    float* __restrict__ wbq, float* __restrict__ bbc0) {
  int blk = blockIdx.x;
  int t = threadIdx.x, wave = t >> 6, lane = t & 63;
  __shared__ float col[D_];
  __shared__ float wsum[4];

  if (blk < 256) {
    int d = blk;
    col[t] = Wk[(size_t)t * D_ + d];          // col[c] = Wk[c][d] (4 wave-gathers, L2-hot)
    __syncthreads();
    float acc = 0.f;
    for (int c4 = 0; c4 < 64; ++c4) {
      float4 kv = ((const float4*)col)[c4];   // aligned LDS broadcast
      acc += kv.x * Wq[(size_t)(4*c4+0) * D_ + t];   // coalesced 1KB rows
      acc += kv.y * Wq[(size_t)(4*c4+1) * D_ + t];
      acc += kv.z * Wq[(size_t)(4*c4+2) * D_ + t];
      acc += kv.w * Wq[(size_t)(4*c4+3) * D_ + t];
    }
    W2[(size_t)d * D_ + t] = acc;
    float p = bq[t] * col[t];
#pragma unroll
    for (int off = 32; off >= 1; off >>= 1) p += __shfl_xor(p, off);
    if (lane == 0) wsum[wave] = p;
    __syncthreads();
    if (t == 0) wbq[d] = wsum[0] + wsum[1] + wsum[2] + wsum[3];
  } else {
    float acc = 0.f;
    for (int c = 0; c < D_; ++c)
      acc += bk[c] * Wq[(size_t)c * D_ + t];
    bbc0[t] = acc;
    float p = bq[t] * bk[t];
#pragma unroll
    for (int off = 32; off >= 1; off >>= 1) p += __shfl_xor(p, off);
    if (lane == 0) wsum[wave] = p;
    __syncthreads();
    if (t == 0) bbc0[D_] = wsum[0] + wsum[1] + wsum[2] + wsum[3];
  }
}

// ---- K1: 240 blocks. k2f[l] = f_w[l]@W2 + bb ; sv[l] = f_w[l].wbq + c0 ----
__global__ __launch_bounds__(256) void k2row(const float* __restrict__ f_w,
    const float* __restrict__ W2, const float* __restrict__ wbq,
    const float* __restrict__ bbc0, float* __restrict__ k2f,
    float* __restrict__ sv) {
  int l = blockIdx.x;
  int t = threadIdx.x, wave = t >> 6, lane = t & 63;
  __shared__ float fw[D_];
  __shared__ float wsum[4];
  fw[t] = f_w[(size_t)l * D_ + t];
  __syncthreads();
  float acc = 0.f;
  for (int d4 = 0; d4 < 64; ++d4) {
    float4 fv = ((const float4*)fw)[d4];      // aligned LDS broadcast
    acc += fv.x * W2[(size_t)(4*d4+0) * D_ + t];     // coalesced W2 rows
    acc += fv.y * W2[(size_t)(4*d4+1) * D_ + t];
    acc += fv.z * W2[(size_t)(4*d4+2) * D_ + t];
    acc += fv.w * W2[(size_t)(4*d4+3) * D_ + t];
  }
  k2f[(size_t)l * D_ + t] = acc + bbc0[t];
  float p = fw[t] * wbq[t];
#pragma unroll
  for (int off = 32; off >= 1; off >>= 1) p += __shfl_xor(p, off);
  if (lane == 0) wsum[wave] = p;
  __syncthreads();
  if (t == 0) sv[l] = wsum[0] + wsum[1] + wsum[2] + wsum[3] + bbc0[D_];
}

// ---- K2: 256 blocks x 4 n-rows: aw=(f_b.k2f+s)*scale -> softmax(L) -> f_bq ----
__global__ __launch_bounds__(256) void aw_fbq(const float* __restrict__ f_b,
    const float* __restrict__ f_w, const float* __restrict__ f_s,
    const float* __restrict__ qmask, const float* __restrict__ lmask,
    const float* __restrict__ k2f, const float* __restrict__ sv,
    float* __restrict__ fbq) {
  int blk = blockIdx.x;           // 256 blocks: b = blk/32, n0 = (blk%32)*4
  int b = blk >> 5, n0 = (blk & 31) * 4;
  int t = threadIdx.x;

  __shared__ float k2l[L_][D_ + 1];   // pad 257: conflict-free
  __shared__ float fbl[4][D_ + 1];
  __shared__ float awl[4][32];
  __shared__ float slds[32];

  for (int r = 0; r < 4; ++r)
    fbl[r][t] = f_b[(size_t)(b * N_ + n0 + r) * D_ + t];
  for (int l = 0; l < L_; ++l)
    k2l[l][t] = k2f[(size_t)(b * L_ + l) * D_ + t];
  if (t < L_) slds[t] = sv[b * L_ + t];
  __syncthreads();

  if (t < 120) {
    int r = t / 30, l = t % 30;
    const float* fr = fbl[r];
    const float* kr = k2l[l];
    float acc = 0.f;
#pragma unroll 8
    for (int j = 0; j < D_; ++j) acc += fr[j] * kr[j];   // fr broadcast, kr CF
    float aw = (acc + slds[l]) * SCALE;
    float qm = qmask[b * L_ + l];
    awl[r][l] = (qm == 0.f) ? NEGV : aw * qm;
  }
  __syncthreads();

  if (t < 4) {
    float mx = -1e30f;
    for (int l = 0; l < L_; ++l) mx = fmaxf(mx, awl[t][l]);
    float s = 0.f;
    for (int l = 0; l < L_; ++l) { float e = __expf(awl[t][l] - mx); awl[t][l] = e; s += e; }
    float inv = 1.f / s;
    for (int l = 0; l < L_; ++l) awl[t][l] *= inv;
  }
  __syncthreads();

  for (int l = 0; l < L_; ++l)            // reuse k2l for f_w rows
    k2l[l][t] = f_w[(size_t)(b * L_ + l) * D_ + t];
  __syncthreads();

  float fsd = f_s[b * D_ + t];
  for (int r = 0; r < 4; ++r) {
    float facc = 0.f;
#pragma unroll
    for (int l = 0; l < L_; ++l) facc += awl[r][l] * k2l[l][t];
    float lm = lmask[b * N_ + n0 + r];
    fbq[(size_t)(b * N_ + n0 + r) * D_ + t] = fbl[r][t] * (facc * lm + fsd);
  }
}

// ---- K3 (measured 35.6us, byte-identical R5/R9/R12): A-row softmax + f_bb fold + stream ----
__global__ __launch_bounds__(256) void fused_stream(const float* __restrict__ f_b,
    const float* __restrict__ f_m, const float* __restrict__ f_s,
    const float* __restrict__ lmask, const float* __restrict__ fbq,
    float* __restrict__ out) {
  int bn = blockIdx.x, b = bn >> 7, n = bn & 127;
  int t = threadIdx.x, w = t >> 6, lane = t & 63;

  __shared__ float part[4][32][65];   // 33.3 KB
  __shared__ float a_lds[N_];
  __shared__ float sm[8];
  __shared__ float4 red[3][64];       // 3 KB

  const float4* fmb = (const float4*)(f_m + (size_t)bn * N_ * D_);
  const float4* fbb = (const float4*)(f_b + (size_t)b * N_ * D_);
  int m0 = w * 32;                    // wave's m-range [m0, m0+32)

  float4 pA[8], pB[8];
#pragma unroll
  for (int i = 0; i < 8; ++i) pA[i] = fmb[(size_t)(m0 + i) * 64 + lane];
  __builtin_amdgcn_sched_barrier(0);

  float4 qv = ((const float4*)(fbq + (size_t)bn * D_))[lane];
#pragma unroll 8
  for (int i = 0; i < 32; ++i) {
    float4 v = ((const float4*)(fbq + (size_t)(b * N_ + m0 + i) * D_))[lane];
    part[w][i][lane] = v.x*qv.x + v.y*qv.y + v.z*qv.z + v.w*qv.w;
  }
  __syncthreads();
  float s = 0.f;
#pragma unroll
  for (int j = 0; j < 32; ++j)
    s += part[w][lane & 31][(lane >> 5) * 32 + j];
  s += __shfl_xor(s, 32);
  if (lane < 32) a_lds[m0 + (lane & 31)] = s;
  __syncthreads();

  float lmn = lmask[b * N_ + n];
  float e = 0.f;
  if (t < N_) {
    float lm = lmask[b * N_ + t];
    float v = (lm == 0.f) ? NEGV : a_lds[t] * SCALE * lm;
    float mx = v;
#pragma unroll
    for (int off = 32; off >= 1; off >>= 1) mx = fmaxf(mx, __shfl_xor(mx, off));
    if (lane == 0) sm[w] = mx;
  }
  __syncthreads();
  if (t < N_) {
    float lm = lmask[b * N_ + t];
    float v = (lm == 0.f) ? NEGV : a_lds[t] * SCALE * lm;
    float gmax = fmaxf(sm[0], sm[1]);
    e = __expf(v - gmax);
    float ss = e;
#pragma unroll
    for (int off = 32; off >= 1; off >>= 1) ss += __shfl_xor(ss, off);
    if (lane == 0) sm[4 + w] = ss;
  }
  __syncthreads();
  if (t < N_) {
    float tot = sm[4] + sm[5];
    a_lds[t] = e * (lmn / tot);
  }
  __syncthreads();

  float4 fs4 = ((const float4*)(f_s + (size_t)b * D_))[lane];
  const float CLOG = -1.44269504088896f;  // -log2(e)
  float4 cs;
  cs.x = fs4.x * CLOG; cs.y = fs4.y * CLOG;
  cs.z = fs4.z * CLOG; cs.w = fs4.w * CLOG;
  float4 acc = make_float4(0.f, 0.f, 0.f, 0.f);

  auto compute8 = [&](float4 (&P)[8], int mbase) {
#pragma unroll
    for (int i = 0; i < 8; ++i) {
      int m = mbase + i;
      float a = a_lds[m];
      float4 fb4 = fbb[(size_t)m * 64 + lane];
      float4 fm4 = P[i];
      float gx = __builtin_amdgcn_rcpf(1.f + __builtin_amdgcn_exp2f(fm4.x * cs.x));
      float gy = __builtin_amdgcn_rcpf(1.f + __builtin_amdgcn_exp2f(fm4.y * cs.y));
      float gz = __builtin_amdgcn_rcpf(1.f + __builtin_amdgcn_exp2f(fm4.z * cs.z));
      float gw = __builtin_amdgcn_rcpf(1.f + __builtin_amdgcn_exp2f(fm4.w * cs.w));
      acc.x += a * (lmn * fb4.x + gx * fm4.x);
      acc.y += a * (lmn * fb4.y + gy * fm4.y);
      acc.z += a * (lmn * fb4.z + gz * fm4.z);
      acc.w += a * (lmn * fb4.w + gw * fm4.w);
    }
  };

#pragma unroll
  for (int i = 0; i < 8; ++i) pB[i] = fmb[(size_t)(m0 + 8 + i) * 64 + lane];
  compute8(pA, m0);
#pragma unroll
  for (int i = 0; i < 8; ++i) pA[i] = fmb[(size_t)(m0 + 16 + i) * 64 + lane];
  compute8(pB, m0 + 8);
#pragma unroll
  for (int i = 0; i < 8; ++i) pB[i] = fmb[(size_t)(m0 + 24 + i) * 64 + lane];
  compute8(pA, m0 + 16);
  compute8(pB, m0 + 24);

  if (w > 0) red[w - 1][lane] = acc;
  __syncthreads();
  if (w == 0) {
#pragma unroll
    for (int j = 0; j < 3; ++j) {
      float4 r4 = red[j][lane];
      acc.x += r4.x; acc.y += r4.y; acc.z += r4.z; acc.w += r4.w;
    }
    float4 fbn = fbb[(size_t)n * 64 + lane];
    float4 o;
    o.x = fbn.x + acc.x;
    o.y = fbn.y + acc.y;
    o.z = fbn.z + acc.z;
    o.w = fbn.w + acc.w;
    ((float4*)out)[(size_t)bn * 64 + lane] = o;
  }
}

extern "C" void kernel_launch(void* const* d_in, const int* in_sizes, int n_in,
                              void* d_out, int out_size, void* d_ws, size_t ws_size,
                              hipStream_t stream) {
  const float* f_b   = (const float*)d_in[0];
  const float* f_w   = (const float*)d_in[1];
  const float* f_s   = (const float*)d_in[2];
  const float* f_m   = (const float*)d_in[3];
  const float* qmask = (const float*)d_in[4];
  const float* lmask = (const float*)d_in[5];
  const float* Wq    = (const float*)d_in[6];
  const float* bq    = (const float*)d_in[7];
  const float* Wk    = (const float*)d_in[8];
  const float* bk    = (const float*)d_in[9];
  float* out = (float*)d_out;

  float* ws   = (float*)d_ws;
  float* W2   = ws;                         // 65536
  float* wbq  = ws + 65536;                 // 256
  float* bbc0 = ws + 66048;                 // 257
  float* k2f  = ws + 131072;                // 61440
  float* sv   = ws + 196608;                // 240
  float* fbq  = ws + 262144;                // 262144

  hipLaunchKernelGGL(w2prep, dim3(257), dim3(256), 0, stream,
                     Wk, Wq, bq, bk, W2, wbq, bbc0);
  hipLaunchKernelGGL(k2row, dim3(B_ * L_), dim3(256), 0, stream,
                     f_w, W2, wbq, bbc0, k2f, sv);
  hipLaunchKernelGGL(aw_fbq, dim3(256), dim3(256), 0, stream,
                     f_b, f_w, f_s, qmask, lmask, k2f, sv, fbq);
  hipLaunchKernelGGL(fused_stream, dim3(B_ * N_), dim3(256), 0, stream,
                     f_b, f_m, f_s, lmask, fbq, out);
}

// Round 14
// 62.348 us; speedup vs baseline: 2.2030x; 1.0289x over previous
//
#include <hip/hip_runtime.h>
#include <math.h>

#define B_ 8
#define N_ 128
#define L_ 30
#define D_ 256
#define NEGV -1000000000.0f
#define SCALE 0.0625f   // 1/sqrt(256)

// ---- K0: 257 blocks. blocks 0..255 (d=blk): W2[d][t]=sum_c Wk[c][d]*Wq[c][t],
//      wbq[d]=sum_c bq[c]*Wk[c][d]. block 256: bb[t]=sum_c bk[c]*Wq[c][t], c0=bq.bk
__global__ __launch_bounds__(256) void w2prep(const float* __restrict__ Wk,
    const float* __restrict__ Wq, const float* __restrict__ bq,
    const float* __restrict__ bk, float* __restrict__ W2,
    float* __restrict__ wbq, float* __restrict__ bbc0) {
  int blk = blockIdx.x;
  int t = threadIdx.x, wave = t >> 6, lane = t & 63;
  __shared__ float col[D_];
  __shared__ float wsum[4];

  if (blk < 256) {
    int d = blk;
    col[t] = Wk[(size_t)t * D_ + d];          // col[c] = Wk[c][d]
    __syncthreads();
    float a0 = 0.f, a1 = 0.f, a2 = 0.f, a3 = 0.f;   // 4-acc ILP: chain 256 -> 64
#pragma unroll 4
    for (int c4 = 0; c4 < 64; ++c4) {
      float4 kv = ((const float4*)col)[c4];   // aligned LDS broadcast
      a0 += kv.x * Wq[(size_t)(4*c4+0) * D_ + t];   // coalesced 1KB rows
      a1 += kv.y * Wq[(size_t)(4*c4+1) * D_ + t];
      a2 += kv.z * Wq[(size_t)(4*c4+2) * D_ + t];
      a3 += kv.w * Wq[(size_t)(4*c4+3) * D_ + t];
    }
    W2[(size_t)d * D_ + t] = (a0 + a1) + (a2 + a3);
    float p = bq[t] * col[t];
#pragma unroll
    for (int off = 32; off >= 1; off >>= 1) p += __shfl_xor(p, off);
    if (lane == 0) wsum[wave] = p;
    __syncthreads();
    if (t == 0) wbq[d] = wsum[0] + wsum[1] + wsum[2] + wsum[3];
  } else {
    float a0 = 0.f, a1 = 0.f, a2 = 0.f, a3 = 0.f;
#pragma unroll 4
    for (int c = 0; c < D_; c += 4) {
      a0 += bk[c + 0] * Wq[(size_t)(c + 0) * D_ + t];
      a1 += bk[c + 1] * Wq[(size_t)(c + 1) * D_ + t];
      a2 += bk[c + 2] * Wq[(size_t)(c + 2) * D_ + t];
      a3 += bk[c + 3] * Wq[(size_t)(c + 3) * D_ + t];
    }
    bbc0[t] = (a0 + a1) + (a2 + a3);
    float p = bq[t] * bk[t];
#pragma unroll
    for (int off = 32; off >= 1; off >>= 1) p += __shfl_xor(p, off);
    if (lane == 0) wsum[wave] = p;
    __syncthreads();
    if (t == 0) bbc0[D_] = wsum[0] + wsum[1] + wsum[2] + wsum[3];
  }
}

// ---- K1: 240 blocks. k2f[l] = f_w[l]@W2 + bb ; sv[l] = f_w[l].wbq + c0 ----
__global__ __launch_bounds__(256) void k2row(const float* __restrict__ f_w,
    const float* __restrict__ W2, const float* __restrict__ wbq,
    const float* __restrict__ bbc0, float* __restrict__ k2f,
    float* __restrict__ sv) {
  int l = blockIdx.x;
  int t = threadIdx.x, wave = t >> 6, lane = t & 63;
  __shared__ float fw[D_];
  __shared__ float wsum[4];
  fw[t] = f_w[(size_t)l * D_ + t];
  __syncthreads();
  float a0 = 0.f, a1 = 0.f, a2 = 0.f, a3 = 0.f;     // 4-acc ILP
#pragma unroll 4
  for (int d4 = 0; d4 < 64; ++d4) {
    float4 fv = ((const float4*)fw)[d4];
    a0 += fv.x * W2[(size_t)(4*d4+0) * D_ + t];
    a1 += fv.y * W2[(size_t)(4*d4+1) * D_ + t];
    a2 += fv.z * W2[(size_t)(4*d4+2) * D_ + t];
    a3 += fv.w * W2[(size_t)(4*d4+3) * D_ + t];
  }
  k2f[(size_t)l * D_ + t] = (a0 + a1) + (a2 + a3) + bbc0[t];
  float p = fw[t] * wbq[t];
#pragma unroll
  for (int off = 32; off >= 1; off >>= 1) p += __shfl_xor(p, off);
  if (lane == 0) wsum[wave] = p;
  __syncthreads();
  if (t == 0) sv[l] = wsum[0] + wsum[1] + wsum[2] + wsum[3] + bbc0[D_];
}

// ---- K2: 256 blocks x 4 n-rows: aw=(f_b.k2f+s)*scale -> softmax(L) -> f_bq ----
__global__ __launch_bounds__(256) void aw_fbq(const float* __restrict__ f_b,
    const float* __restrict__ f_w, const float* __restrict__ f_s,
    const float* __restrict__ qmask, const float* __restrict__ lmask,
    const float* __restrict__ k2f, const float* __restrict__ sv,
    float* __restrict__ fbq) {
  int blk = blockIdx.x;           // 256 blocks: b = blk/32, n0 = (blk%32)*4
  int b = blk >> 5, n0 = (blk & 31) * 4;
  int t = threadIdx.x;

  __shared__ float k2l[L_][260];      // stride 260: rows 16B-aligned (1040B)
  __shared__ float fbl[4][260];
  __shared__ float pdot[120][2];
  __shared__ float awl[4][32];
  __shared__ float slds[32];

  for (int r = 0; r < 4; ++r)
    fbl[r][t] = f_b[(size_t)(b * N_ + n0 + r) * D_ + t];
  for (int l = 0; l < L_; ++l)
    k2l[l][t] = k2f[(size_t)(b * L_ + l) * D_ + t];
  if (t < L_) slds[t] = sv[b * L_ + t];
  __syncthreads();

  // dot split: 240 threads = 120 (r,l) pairs x 2 halves of 128 elements
  if (t < 240) {
    int p = t % 120, half = t / 120;
    int r = p / 30, l = p % 30;
    const float4* fr = (const float4*)(fbl[r] + half * 128);   // broadcast-ish
    const float4* kr = (const float4*)(k2l[l] + half * 128);   // ~4-way CF
    float ac[4] = {0.f, 0.f, 0.f, 0.f};
#pragma unroll
    for (int j = 0; j < 32; ++j) {
      float4 fv = fr[j], kv = kr[j];
      ac[j & 3] += fv.x*kv.x + fv.y*kv.y + fv.z*kv.z + fv.w*kv.w;
    }
    pdot[p][half] = (ac[0] + ac[1]) + (ac[2] + ac[3]);
  }
  __syncthreads();

  if (t < 120) {
    int r = t / 30, l = t % 30;
    float acc = pdot[t][0] + pdot[t][1];
    float aw = (acc + slds[l]) * SCALE;
    float qm = qmask[b * L_ + l];
    awl[r][l] = (qm == 0.f) ? NEGV : aw * qm;
  }
  __syncthreads();

  if (t < 4) {
    float mx = -1e30f;
    for (int l = 0; l < L_; ++l) mx = fmaxf(mx, awl[t][l]);
    float s = 0.f;
    for (int l = 0; l < L_; ++l) { float e = __expf(awl[t][l] - mx); awl[t][l] = e; s += e; }
    float inv = 1.f / s;
    for (int l = 0; l < L_; ++l) awl[t][l] *= inv;
  }
  __syncthreads();

  for (int l = 0; l < L_; ++l)            // reuse k2l for f_w rows
    k2l[l][t] = f_w[(size_t)(b * L_ + l) * D_ + t];
  __syncthreads();

  float fsd = f_s[b * D_ + t];
  for (int r = 0; r < 4; ++r) {
    float f0 = 0.f, f1 = 0.f;
#pragma unroll
    for (int l = 0; l < L_; l += 2) {     // 2-acc ILP (L=30 even)
      f0 += awl[r][l] * k2l[l][t];
      f1 += awl[r][l + 1] * k2l[l + 1][t];
    }
    float lm = lmask[b * N_ + n0 + r];
    fbq[(size_t)(b * N_ + n0 + r) * D_ + t] = fbl[r][t] * ((f0 + f1) * lm + fsd);
  }
}

// ---- K3 (measured 35.6us, byte-identical R5/R9/R12/R13): A softmax + fb fold + stream ----
__global__ __launch_bounds__(256) void fused_stream(const float* __restrict__ f_b,
    const float* __restrict__ f_m, const float* __restrict__ f_s,
    const float* __restrict__ lmask, const float* __restrict__ fbq,
    float* __restrict__ out) {
  int bn = blockIdx.x, b = bn >> 7, n = bn & 127;
  int t = threadIdx.x, w = t >> 6, lane = t & 63;

  __shared__ float part[4][32][65];   // 33.3 KB
  __shared__ float a_lds[N_];
  __shared__ float sm[8];
  __shared__ float4 red[3][64];       // 3 KB

  const float4* fmb = (const float4*)(f_m + (size_t)bn * N_ * D_);
  const float4* fbb = (const float4*)(f_b + (size_t)b * N_ * D_);
  int m0 = w * 32;                    // wave's m-range [m0, m0+32)

  float4 pA[8], pB[8];
#pragma unroll
  for (int i = 0; i < 8; ++i) pA[i] = fmb[(size_t)(m0 + i) * 64 + lane];
  __builtin_amdgcn_sched_barrier(0);

  float4 qv = ((const float4*)(fbq + (size_t)bn * D_))[lane];
#pragma unroll 8
  for (int i = 0; i < 32; ++i) {
    float4 v = ((const float4*)(fbq + (size_t)(b * N_ + m0 + i) * D_))[lane];
    part[w][i][lane] = v.x*qv.x + v.y*qv.y + v.z*qv.z + v.w*qv.w;
  }
  __syncthreads();
  float s = 0.f;
#pragma unroll
  for (int j = 0; j < 32; ++j)
    s += part[w][lane & 31][(lane >> 5) * 32 + j];
  s += __shfl_xor(s, 32);
  if (lane < 32) a_lds[m0 + (lane & 31)] = s;
  __syncthreads();

  float lmn = lmask[b * N_ + n];
  float e = 0.f;
  if (t < N_) {
    float lm = lmask[b * N_ + t];
    float v = (lm == 0.f) ? NEGV : a_lds[t] * SCALE * lm;
    float mx = v;
#pragma unroll
    for (int off = 32; off >= 1; off >>= 1) mx = fmaxf(mx, __shfl_xor(mx, off));
    if (lane == 0) sm[w] = mx;
  }
  __syncthreads();
  if (t < N_) {
    float lm = lmask[b * N_ + t];
    float v = (lm == 0.f) ? NEGV : a_lds[t] * SCALE * lm;
    float gmax = fmaxf(sm[0], sm[1]);
    e = __expf(v - gmax);
    float ss = e;
#pragma unroll
    for (int off = 32; off >= 1; off >>= 1) ss += __shfl_xor(ss, off);
    if (lane == 0) sm[4 + w] = ss;
  }
  __syncthreads();
  if (t < N_) {
    float tot = sm[4] + sm[5];
    a_lds[t] = e * (lmn / tot);
  }
  __syncthreads();

  float4 fs4 = ((const float4*)(f_s + (size_t)b * D_))[lane];
  const float CLOG = -1.44269504088896f;  // -log2(e)
  float4 cs;
  cs.x = fs4.x * CLOG; cs.y = fs4.y * CLOG;
  cs.z = fs4.z * CLOG; cs.w = fs4.w * CLOG;
  float4 acc = make_float4(0.f, 0.f, 0.f, 0.f);

  auto compute8 = [&](float4 (&P)[8], int mbase) {
#pragma unroll
    for (int i = 0; i < 8; ++i) {
      int m = mbase + i;
      float a = a_lds[m];
      float4 fb4 = fbb[(size_t)m * 64 + lane];
      float4 fm4 = P[i];
      float gx = __builtin_amdgcn_rcpf(1.f + __builtin_amdgcn_exp2f(fm4.x * cs.x));
      float gy = __builtin_amdgcn_rcpf(1.f + __builtin_amdgcn_exp2f(fm4.y * cs.y));
      float gz = __builtin_amdgcn_rcpf(1.f + __builtin_amdgcn_exp2f(fm4.z * cs.z));
      float gw = __builtin_amdgcn_rcpf(1.f + __builtin_amdgcn_exp2f(fm4.w * cs.w));
      acc.x += a * (lmn * fb4.x + gx * fm4.x);
      acc.y += a * (lmn * fb4.y + gy * fm4.y);
      acc.z += a * (lmn * fb4.z + gz * fm4.z);
      acc.w += a * (lmn * fb4.w + gw * fm4.w);
    }
  };

#pragma unroll
  for (int i = 0; i < 8; ++i) pB[i] = fmb[(size_t)(m0 + 8 + i) * 64 + lane];
  compute8(pA, m0);
#pragma unroll
  for (int i = 0; i < 8; ++i) pA[i] = fmb[(size_t)(m0 + 16 + i) * 64 + lane];
  compute8(pB, m0 + 8);
#pragma unroll
  for (int i = 0; i < 8; ++i) pB[i] = fmb[(size_t)(m0 + 24 + i) * 64 + lane];
  compute8(pA, m0 + 16);
  compute8(pB, m0 + 24);

  if (w > 0) red[w - 1][lane] = acc;
  __syncthreads();
  if (w == 0) {
#pragma unroll
    for (int j = 0; j < 3; ++j) {
      float4 r4 = red[j][lane];
      acc.x += r4.x; acc.y += r4.y; acc.z += r4.z; acc.w += r4.w;
    }
    float4 fbn = fbb[(size_t)n * 64 + lane];
    float4 o;
    o.x = fbn.x + acc.x;
    o.y = fbn.y + acc.y;
    o.z = fbn.z + acc.z;
    o.w = fbn.w + acc.w;
    ((float4*)out)[(size_t)bn * 64 + lane] = o;
  }
}

extern "C" void kernel_launch(void* const* d_in, const int* in_sizes, int n_in,
                              void* d_out, int out_size, void* d_ws, size_t ws_size,
                              hipStream_t stream) {
  const float* f_b   = (const float*)d_in[0];
  const float* f_w   = (const float*)d_in[1];
  const float* f_s   = (const float*)d_in[2];
  const float* f_m   = (const float*)d_in[3];
  const float* qmask = (const float*)d_in[4];
  const float* lmask = (const float*)d_in[5];
  const float* Wq    = (const float*)d_in[6];
  const float* bq    = (const float*)d_in[7];
  const float* Wk    = (const float*)d_in[8];
  const float* bk    = (const float*)d_in[9];
  float* out = (float*)d_out;

  float* ws   = (float*)d_ws;
  float* W2   = ws;                         // 65536
  float* wbq  = ws + 65536;                 // 256
  float* bbc0 = ws + 66048;                 // 257
  float* k2f  = ws + 131072;                // 61440
  float* sv   = ws + 196608;                // 240
  float* fbq  = ws + 262144;                // 262144

  hipLaunchKernelGGL(w2prep, dim3(257), dim3(256), 0, stream,
                     Wk, Wq, bq, bk, W2, wbq, bbc0);
  hipLaunchKernelGGL(k2row, dim3(B_ * L_), dim3(256), 0, stream,
                     f_w, W2, wbq, bbc0, k2f, sv);
  hipLaunchKernelGGL(aw_fbq, dim3(256), dim3(256), 0, stream,
                     f_b, f_w, f_s, qmask, lmask, k2f, sv, fbq);
  hipLaunchKernelGGL(fused_stream, dim3(B_ * N_), dim3(256), 0, stream,
                     f_b, f_m, f_s, lmask, fbq, out);
}

// Round 15
// 57.887 us; speedup vs baseline: 2.3728x; 1.0771x over previous
//
#include <hip/hip_runtime.h>
#include <math.h>

#define B_ 8
#define N_ 128
#define L_ 30
#define D_ 256
#define NEGV -1000000000.0f
#define SCALE 0.0625f   // 1/sqrt(256)

// ---- K0: 240 blocks, block l: k[l]=f_w[l]@Wk^T+bk ; k2f[l]=k[l]@Wq ; sv[l]=bq.k[l] ----
__global__ __launch_bounds__(256) void kk2(const float* __restrict__ f_w,
    const float* __restrict__ Wk, const float* __restrict__ bk,
    const float* __restrict__ Wq, const float* __restrict__ bq,
    float* __restrict__ k2f, float* __restrict__ sv) {
  int l = blockIdx.x;              // 240
  int t = threadIdx.x, wave = t >> 6, lane = t & 63;
  __shared__ float part[4][16][65];
  __shared__ float kl[D_];
  __shared__ float wsum[4];

  float4 x4 = ((const float4*)(f_w + (size_t)l * D_))[lane];   // whole row per wave

  // phase 1: k[l][c] via coalesced Wk-row loads + LDS transpose-reduce
  for (int g = 0; g < 4; ++g) {
    int dbase = wave * 64 + g * 16;
#pragma unroll
    for (int i = 0; i < 16; ++i) {
      float4 w4 = ((const float4*)(Wk + (size_t)(dbase + i) * D_))[lane];  // 1KB coalesced
      part[wave][i][lane] = w4.x*x4.x + w4.y*x4.y + w4.z*x4.z + w4.w*x4.w;
    }
    float s = 0.f;
#pragma unroll
    for (int j = 0; j < 16; ++j)
      s += part[wave][lane & 15][(lane >> 4) * 16 + j];   // CF (pad 65)
    s += __shfl_xor(s, 16);
    s += __shfl_xor(s, 32);
    if (lane < 16) kl[dbase + lane] = s + bk[dbase + lane];
  }
  __syncthreads();

  // phase 2: k2f[l][t] = sum_d kl[d]*Wq[d][t]  (4-acc ILP, coalesced Wq rows)
  float a0 = 0.f, a1 = 0.f, a2 = 0.f, a3 = 0.f;
#pragma unroll 4
  for (int d4 = 0; d4 < 64; ++d4) {
    float4 kv = ((const float4*)kl)[d4];                 // aligned LDS broadcast
    a0 += kv.x * Wq[(size_t)(4*d4+0) * D_ + t];
    a1 += kv.y * Wq[(size_t)(4*d4+1) * D_ + t];
    a2 += kv.z * Wq[(size_t)(4*d4+2) * D_ + t];
    a3 += kv.w * Wq[(size_t)(4*d4+3) * D_ + t];
  }
  k2f[(size_t)l * D_ + t] = (a0 + a1) + (a2 + a3);

  // phase 3: sv[l] = bq . k[l]
  float p = bq[t] * kl[t];
#pragma unroll
  for (int off = 32; off >= 1; off >>= 1) p += __shfl_xor(p, off);
  if (lane == 0) wsum[wave] = p;
  __syncthreads();
  if (t == 0) sv[l] = wsum[0] + wsum[1] + wsum[2] + wsum[3];
}

// ---- K1 (R14-proven): 256 blocks x 4 n-rows: aw=(f_b.k2f+sv)*scale -> softmax -> f_bq ----
__global__ __launch_bounds__(256) void aw_fbq(const float* __restrict__ f_b,
    const float* __restrict__ f_w, const float* __restrict__ f_s,
    const float* __restrict__ qmask, const float* __restrict__ lmask,
    const float* __restrict__ k2f, const float* __restrict__ sv,
    float* __restrict__ fbq) {
  int blk = blockIdx.x;           // 256 blocks: b = blk/32, n0 = (blk%32)*4
  int b = blk >> 5, n0 = (blk & 31) * 4;
  int t = threadIdx.x;

  __shared__ float k2l[L_][260];      // stride 260: rows 16B-aligned
  __shared__ float fbl[4][260];
  __shared__ float pdot[120][2];
  __shared__ float awl[4][32];
  __shared__ float slds[32];

  for (int r = 0; r < 4; ++r)
    fbl[r][t] = f_b[(size_t)(b * N_ + n0 + r) * D_ + t];
  for (int l = 0; l < L_; ++l)
    k2l[l][t] = k2f[(size_t)(b * L_ + l) * D_ + t];
  if (t < L_) slds[t] = sv[b * L_ + t];
  __syncthreads();

  if (t < 240) {
    int p = t % 120, half = t / 120;
    int r = p / 30, l = p % 30;
    const float4* fr = (const float4*)(fbl[r] + half * 128);
    const float4* kr = (const float4*)(k2l[l] + half * 128);
    float ac[4] = {0.f, 0.f, 0.f, 0.f};
#pragma unroll
    for (int j = 0; j < 32; ++j) {
      float4 fv = fr[j], kv = kr[j];
      ac[j & 3] += fv.x*kv.x + fv.y*kv.y + fv.z*kv.z + fv.w*kv.w;
    }
    pdot[p][half] = (ac[0] + ac[1]) + (ac[2] + ac[3]);
  }
  __syncthreads();

  if (t < 120) {
    int r = t / 30, l = t % 30;
    float acc = pdot[t][0] + pdot[t][1];
    float aw = (acc + slds[l]) * SCALE;
    float qm = qmask[b * L_ + l];
    awl[r][l] = (qm == 0.f) ? NEGV : aw * qm;
  }
  __syncthreads();

  if (t < 4) {
    float mx = -1e30f;
    for (int l = 0; l < L_; ++l) mx = fmaxf(mx, awl[t][l]);
    float s = 0.f;
    for (int l = 0; l < L_; ++l) { float e = __expf(awl[t][l] - mx); awl[t][l] = e; s += e; }
    float inv = 1.f / s;
    for (int l = 0; l < L_; ++l) awl[t][l] *= inv;
  }
  __syncthreads();

  for (int l = 0; l < L_; ++l)            // reuse k2l for f_w rows
    k2l[l][t] = f_w[(size_t)(b * L_ + l) * D_ + t];
  __syncthreads();

  float fsd = f_s[b * D_ + t];
  for (int r = 0; r < 4; ++r) {
    float f0 = 0.f, f1 = 0.f;
#pragma unroll
    for (int l = 0; l < L_; l += 2) {
      f0 += awl[r][l] * k2l[l][t];
      f1 += awl[r][l + 1] * k2l[l + 1][t];
    }
    float lm = lmask[b * N_ + n0 + r];
    fbq[(size_t)(b * N_ + n0 + r) * D_ + t] = fbl[r][t] * ((f0 + f1) * lm + fsd);
  }
}

// ---- K2 (measured 35.6us, byte-identical): A softmax + fb fold + sigmoid f_m stream ----
__global__ __launch_bounds__(256) void fused_stream(const float* __restrict__ f_b,
    const float* __restrict__ f_m, const float* __restrict__ f_s,
    const float* __restrict__ lmask, const float* __restrict__ fbq,
    float* __restrict__ out) {
  int bn = blockIdx.x, b = bn >> 7, n = bn & 127;
  int t = threadIdx.x, w = t >> 6, lane = t & 63;

  __shared__ float part[4][32][65];   // 33.3 KB
  __shared__ float a_lds[N_];
  __shared__ float sm[8];
  __shared__ float4 red[3][64];       // 3 KB

  const float4* fmb = (const float4*)(f_m + (size_t)bn * N_ * D_);
  const float4* fbb = (const float4*)(f_b + (size_t)b * N_ * D_);
  int m0 = w * 32;                    // wave's m-range [m0, m0+32)

  float4 pA[8], pB[8];
#pragma unroll
  for (int i = 0; i < 8; ++i) pA[i] = fmb[(size_t)(m0 + i) * 64 + lane];
  __builtin_amdgcn_sched_barrier(0);

  float4 qv = ((const float4*)(fbq + (size_t)bn * D_))[lane];
#pragma unroll 8
  for (int i = 0; i < 32; ++i) {
    float4 v = ((const float4*)(fbq + (size_t)(b * N_ + m0 + i) * D_))[lane];
    part[w][i][lane] = v.x*qv.x + v.y*qv.y + v.z*qv.z + v.w*qv.w;
  }
  __syncthreads();
  float s = 0.f;
#pragma unroll
  for (int j = 0; j < 32; ++j)
    s += part[w][lane & 31][(lane >> 5) * 32 + j];
  s += __shfl_xor(s, 32);
  if (lane < 32) a_lds[m0 + (lane & 31)] = s;
  __syncthreads();

  float lmn = lmask[b * N_ + n];
  float e = 0.f;
  if (t < N_) {
    float lm = lmask[b * N_ + t];
    float v = (lm == 0.f) ? NEGV : a_lds[t] * SCALE * lm;
    float mx = v;
#pragma unroll
    for (int off = 32; off >= 1; off >>= 1) mx = fmaxf(mx, __shfl_xor(mx, off));
    if (lane == 0) sm[w] = mx;
  }
  __syncthreads();
  if (t < N_) {
    float lm = lmask[b * N_ + t];
    float v = (lm == 0.f) ? NEGV : a_lds[t] * SCALE * lm;
    float gmax = fmaxf(sm[0], sm[1]);
    e = __expf(v - gmax);
    float ss = e;
#pragma unroll
    for (int off = 32; off >= 1; off >>= 1) ss += __shfl_xor(ss, off);
    if (lane == 0) sm[4 + w] = ss;
  }
  __syncthreads();
  if (t < N_) {
    float tot = sm[4] + sm[5];
    a_lds[t] = e * (lmn / tot);
  }
  __syncthreads();

  float4 fs4 = ((const float4*)(f_s + (size_t)b * D_))[lane];
  const float CLOG = -1.44269504088896f;  // -log2(e)
  float4 cs;
  cs.x = fs4.x * CLOG; cs.y = fs4.y * CLOG;
  cs.z = fs4.z * CLOG; cs.w = fs4.w * CLOG;
  float4 acc = make_float4(0.f, 0.f, 0.f, 0.f);

  auto compute8 = [&](float4 (&P)[8], int mbase) {
#pragma unroll
    for (int i = 0; i < 8; ++i) {
      int m = mbase + i;
      float a = a_lds[m];
      float4 fb4 = fbb[(size_t)m * 64 + lane];
      float4 fm4 = P[i];
      float gx = __builtin_amdgcn_rcpf(1.f + __builtin_amdgcn_exp2f(fm4.x * cs.x));
      float gy = __builtin_amdgcn_rcpf(1.f + __builtin_amdgcn_exp2f(fm4.y * cs.y));
      float gz = __builtin_amdgcn_rcpf(1.f + __builtin_amdgcn_exp2f(fm4.z * cs.z));
      float gw = __builtin_amdgcn_rcpf(1.f + __builtin_amdgcn_exp2f(fm4.w * cs.w));
      acc.x += a * (lmn * fb4.x + gx * fm4.x);
      acc.y += a * (lmn * fb4.y + gy * fm4.y);
      acc.z += a * (lmn * fb4.z + gz * fm4.z);
      acc.w += a * (lmn * fb4.w + gw * fm4.w);
    }
  };

#pragma unroll
  for (int i = 0; i < 8; ++i) pB[i] = fmb[(size_t)(m0 + 8 + i) * 64 + lane];
  compute8(pA, m0);
#pragma unroll
  for (int i = 0; i < 8; ++i) pA[i] = fmb[(size_t)(m0 + 16 + i) * 64 + lane];
  compute8(pB, m0 + 8);
#pragma unroll
  for (int i = 0; i < 8; ++i) pB[i] = fmb[(size_t)(m0 + 24 + i) * 64 + lane];
  compute8(pA, m0 + 16);
  compute8(pB, m0 + 24);

  if (w > 0) red[w - 1][lane] = acc;
  __syncthreads();
  if (w == 0) {
#pragma unroll
    for (int j = 0; j < 3; ++j) {
      float4 r4 = red[j][lane];
      acc.x += r4.x; acc.y += r4.y; acc.z += r4.z; acc.w += r4.w;
    }
    float4 fbn = fbb[(size_t)n * 64 + lane];
    float4 o;
    o.x = fbn.x + acc.x;
    o.y = fbn.y + acc.y;
    o.z = fbn.z + acc.z;
    o.w = fbn.w + acc.w;
    ((float4*)out)[(size_t)bn * 64 + lane] = o;
  }
}

extern "C" void kernel_launch(void* const* d_in, const int* in_sizes, int n_in,
                              void* d_out, int out_size, void* d_ws, size_t ws_size,
                              hipStream_t stream) {
  const float* f_b   = (const float*)d_in[0];
  const float* f_w   = (const float*)d_in[1];
  const float* f_s   = (const float*)d_in[2];
  const float* f_m   = (const float*)d_in[3];
  const float* qmask = (const float*)d_in[4];
  const float* lmask = (const float*)d_in[5];
  const float* Wq    = (const float*)d_in[6];
  const float* bq    = (const float*)d_in[7];
  const float* Wk    = (const float*)d_in[8];
  const float* bk    = (const float*)d_in[9];
  float* out = (float*)d_out;

  float* ws  = (float*)d_ws;
  float* k2f = ws;                          // 61440 (pad 65536)
  float* sv  = ws + 65536;                  // 240  (pad 1024)
  float* fbq = ws + 131072;                 // 262144

  hipLaunchKernelGGL(kk2, dim3(B_ * L_), dim3(256), 0, stream,
                     f_w, Wk, bk, Wq, bq, k2f, sv);
  hipLaunchKernelGGL(aw_fbq, dim3(256), dim3(256), 0, stream,
                     f_b, f_w, f_s, qmask, lmask, k2f, sv, fbq);
  hipLaunchKernelGGL(fused_stream, dim3(B_ * N_), dim3(256), 0, stream,
                     f_b, f_m, f_s, lmask, fbq, out);
}

// Round 16
// 54.708 us; speedup vs baseline: 2.5106x; 1.0581x over previous
//
#include <hip/hip_runtime.h>
#include <math.h>

#define B_ 8
#define N_ 128
#define L_ 30
#define D_ 256
#define NEGV -1000000000.0f
#define SCALE 0.0625f   // 1/sqrt(256)

// ---- K0 (R15-proven): 240 blocks, block l: k[l]=f_w[l]@Wk^T+bk ; k2f[l]=k[l]@Wq ; sv[l]=bq.k[l] ----
__global__ __launch_bounds__(256) void kk2(const float* __restrict__ f_w,
    const float* __restrict__ Wk, const float* __restrict__ bk,
    const float* __restrict__ Wq, const float* __restrict__ bq,
    float* __restrict__ k2f, float* __restrict__ sv) {
  int l = blockIdx.x;              // 240
  int t = threadIdx.x, wave = t >> 6, lane = t & 63;
  __shared__ float part[4][16][65];
  __shared__ float kl[D_];
  __shared__ float wsum[4];

  float4 x4 = ((const float4*)(f_w + (size_t)l * D_))[lane];

  for (int g = 0; g < 4; ++g) {
    int dbase = wave * 64 + g * 16;
#pragma unroll
    for (int i = 0; i < 16; ++i) {
      float4 w4 = ((const float4*)(Wk + (size_t)(dbase + i) * D_))[lane];
      part[wave][i][lane] = w4.x*x4.x + w4.y*x4.y + w4.z*x4.z + w4.w*x4.w;
    }
    float s = 0.f;
#pragma unroll
    for (int j = 0; j < 16; ++j)
      s += part[wave][lane & 15][(lane >> 4) * 16 + j];
    s += __shfl_xor(s, 16);
    s += __shfl_xor(s, 32);
    if (lane < 16) kl[dbase + lane] = s + bk[dbase + lane];
  }
  __syncthreads();

  float a0 = 0.f, a1 = 0.f, a2 = 0.f, a3 = 0.f;
#pragma unroll 4
  for (int d4 = 0; d4 < 64; ++d4) {
    float4 kv = ((const float4*)kl)[d4];
    a0 += kv.x * Wq[(size_t)(4*d4+0) * D_ + t];
    a1 += kv.y * Wq[(size_t)(4*d4+1) * D_ + t];
    a2 += kv.z * Wq[(size_t)(4*d4+2) * D_ + t];
    a3 += kv.w * Wq[(size_t)(4*d4+3) * D_ + t];
  }
  k2f[(size_t)l * D_ + t] = (a0 + a1) + (a2 + a3);

  float p = bq[t] * kl[t];
#pragma unroll
  for (int off = 32; off >= 1; off >>= 1) p += __shfl_xor(p, off);
  if (lane == 0) wsum[wave] = p;
  __syncthreads();
  if (t == 0) sv[l] = wsum[0] + wsum[1] + wsum[2] + wsum[3];
}

// ---- K1 (R14/R15-proven): 256 blocks x 4 n-rows: aw=(f_b.k2f+sv)*scale -> softmax -> f_bq ----
__global__ __launch_bounds__(256) void aw_fbq(const float* __restrict__ f_b,
    const float* __restrict__ f_w, const float* __restrict__ f_s,
    const float* __restrict__ qmask, const float* __restrict__ lmask,
    const float* __restrict__ k2f, const float* __restrict__ sv,
    float* __restrict__ fbq) {
  int blk = blockIdx.x;
  int b = blk >> 5, n0 = (blk & 31) * 4;
  int t = threadIdx.x;

  __shared__ float k2l[L_][260];
  __shared__ float fbl[4][260];
  __shared__ float pdot[120][2];
  __shared__ float awl[4][32];
  __shared__ float slds[32];

  for (int r = 0; r < 4; ++r)
    fbl[r][t] = f_b[(size_t)(b * N_ + n0 + r) * D_ + t];
  for (int l = 0; l < L_; ++l)
    k2l[l][t] = k2f[(size_t)(b * L_ + l) * D_ + t];
  if (t < L_) slds[t] = sv[b * L_ + t];
  __syncthreads();

  if (t < 240) {
    int p = t % 120, half = t / 120;
    int r = p / 30, l = p % 30;
    const float4* fr = (const float4*)(fbl[r] + half * 128);
    const float4* kr = (const float4*)(k2l[l] + half * 128);
    float ac[4] = {0.f, 0.f, 0.f, 0.f};
#pragma unroll
    for (int j = 0; j < 32; ++j) {
      float4 fv = fr[j], kv = kr[j];
      ac[j & 3] += fv.x*kv.x + fv.y*kv.y + fv.z*kv.z + fv.w*kv.w;
    }
    pdot[p][half] = (ac[0] + ac[1]) + (ac[2] + ac[3]);
  }
  __syncthreads();

  if (t < 120) {
    int r = t / 30, l = t % 30;
    float acc = pdot[t][0] + pdot[t][1];
    float aw = (acc + slds[l]) * SCALE;
    float qm = qmask[b * L_ + l];
    awl[r][l] = (qm == 0.f) ? NEGV : aw * qm;
  }
  __syncthreads();

  if (t < 4) {
    float mx = -1e30f;
    for (int l = 0; l < L_; ++l) mx = fmaxf(mx, awl[t][l]);
    float s = 0.f;
    for (int l = 0; l < L_; ++l) { float e = __expf(awl[t][l] - mx); awl[t][l] = e; s += e; }
    float inv = 1.f / s;
    for (int l = 0; l < L_; ++l) awl[t][l] *= inv;
  }
  __syncthreads();

  for (int l = 0; l < L_; ++l)
    k2l[l][t] = f_w[(size_t)(b * L_ + l) * D_ + t];
  __syncthreads();

  float fsd = f_s[b * D_ + t];
  for (int r = 0; r < 4; ++r) {
    float f0 = 0.f, f1 = 0.f;
#pragma unroll
    for (int l = 0; l < L_; l += 2) {
      f0 += awl[r][l] * k2l[l][t];
      f1 += awl[r][l + 1] * k2l[l + 1][t];
    }
    float lm = lmask[b * N_ + n0 + r];
    fbq[(size_t)(b * N_ + n0 + r) * D_ + t] = fbl[r][t] * ((f0 + f1) * lm + fsd);
  }
}

// ---- K2 (v2): A softmax + phase-B fbb column-walk + PURE sigmoid f_m stream ----
// out[n,:] = f_b[n] + lmn*fbb + sum_m A'[n,m]*sigmoid(fm*fs)*fm,  fbb = sum_m A'[n,m]*f_b[m]
__global__ __launch_bounds__(256) void fused_stream(const float* __restrict__ f_b,
    const float* __restrict__ f_m, const float* __restrict__ f_s,
    const float* __restrict__ lmask, const float* __restrict__ fbq,
    float* __restrict__ out) {
  int bn = blockIdx.x, b = bn >> 7, n = bn & 127;
  int t = threadIdx.x, w = t >> 6, lane = t & 63;

  __shared__ float part[4][32][65];   // 33.3 KB
  __shared__ float a_lds[N_];
  __shared__ float sm[8];
  __shared__ float4 red[3][64];       // 3 KB
  __shared__ float fbbred[D_];        // 1 KB

  const float4* fmb = (const float4*)(f_m + (size_t)bn * N_ * D_);
  const float4* fbb = (const float4*)(f_b + (size_t)b * N_ * D_);
  int m0 = w * 32;

  float4 pA[8], pB[8];
#pragma unroll
  for (int i = 0; i < 8; ++i) pA[i] = fmb[(size_t)(m0 + i) * 64 + lane];
  __builtin_amdgcn_sched_barrier(0);

  // Phase A: A-dots
  float4 qv = ((const float4*)(fbq + (size_t)bn * D_))[lane];
#pragma unroll 8
  for (int i = 0; i < 32; ++i) {
    float4 v = ((const float4*)(fbq + (size_t)(b * N_ + m0 + i) * D_))[lane];
    part[w][i][lane] = v.x*qv.x + v.y*qv.y + v.z*qv.z + v.w*qv.w;
  }
  __syncthreads();
  float s = 0.f;
#pragma unroll
  for (int j = 0; j < 32; ++j)
    s += part[w][lane & 31][(lane >> 5) * 32 + j];
  s += __shfl_xor(s, 32);
  if (lane < 32) a_lds[m0 + (lane & 31)] = s;
  __syncthreads();

  // softmax over 128, masked, * lmask[n]
  float lmn = lmask[b * N_ + n];
  float e = 0.f;
  if (t < N_) {
    float lm = lmask[b * N_ + t];
    float v = (lm == 0.f) ? NEGV : a_lds[t] * SCALE * lm;
    float mx = v;
#pragma unroll
    for (int off = 32; off >= 1; off >>= 1) mx = fmaxf(mx, __shfl_xor(mx, off));
    if (lane == 0) sm[w] = mx;
  }
  __syncthreads();
  if (t < N_) {
    float lm = lmask[b * N_ + t];
    float v = (lm == 0.f) ? NEGV : a_lds[t] * SCALE * lm;
    float gmax = fmaxf(sm[0], sm[1]);
    e = __expf(v - gmax);
    float ss = e;
#pragma unroll
    for (int off = 32; off >= 1; off >>= 1) ss += __shfl_xor(ss, off);
    if (lane == 0) sm[4 + w] = ss;
  }
  __syncthreads();
  if (t < N_) {
    float tot = sm[4] + sm[5];
    a_lds[t] = e * (lmn / tot);
  }
  __syncthreads();

  // Phase B: fbb[d] = sum_m a[m] * f_b[b,m,d]  (d = t, coalesced 256B/instr, L2-hot)
  {
    const float* fbcol = f_b + (size_t)b * N_ * D_ + t;
    float f0 = 0.f, f1 = 0.f;
#pragma unroll 8
    for (int m = 0; m < N_; m += 2) {
      f0 += a_lds[m]     * fbcol[(size_t)m * D_];
      f1 += a_lds[m + 1] * fbcol[(size_t)(m + 1) * D_];
    }
    fbbred[t] = f0 + f1;
  }

  // Phase C: PURE f_m sigmoid stream (double-buffered registers)
  float4 fs4 = ((const float4*)(f_s + (size_t)b * D_))[lane];
  const float CLOG = -1.44269504088896f;  // -log2(e)
  float4 cs;
  cs.x = fs4.x * CLOG; cs.y = fs4.y * CLOG;
  cs.z = fs4.z * CLOG; cs.w = fs4.w * CLOG;
  float4 acc = make_float4(0.f, 0.f, 0.f, 0.f);

  auto compute8 = [&](float4 (&P)[8], int mbase) {
#pragma unroll
    for (int i = 0; i < 8; ++i) {
      float a = a_lds[mbase + i];
      float4 fm4 = P[i];
      float gx = __builtin_amdgcn_rcpf(1.f + __builtin_amdgcn_exp2f(fm4.x * cs.x));
      float gy = __builtin_amdgcn_rcpf(1.f + __builtin_amdgcn_exp2f(fm4.y * cs.y));
      float gz = __builtin_amdgcn_rcpf(1.f + __builtin_amdgcn_exp2f(fm4.z * cs.z));
      float gw = __builtin_amdgcn_rcpf(1.f + __builtin_amdgcn_exp2f(fm4.w * cs.w));
      acc.x += a * (gx * fm4.x);
      acc.y += a * (gy * fm4.y);
      acc.z += a * (gz * fm4.z);
      acc.w += a * (gw * fm4.w);
    }
  };

#pragma unroll
  for (int i = 0; i < 8; ++i) pB[i] = fmb[(size_t)(m0 + 8 + i) * 64 + lane];
  compute8(pA, m0);
#pragma unroll
  for (int i = 0; i < 8; ++i) pA[i] = fmb[(size_t)(m0 + 16 + i) * 64 + lane];
  compute8(pB, m0 + 8);
#pragma unroll
  for (int i = 0; i < 8; ++i) pB[i] = fmb[(size_t)(m0 + 24 + i) * 64 + lane];
  compute8(pA, m0 + 16);
  compute8(pB, m0 + 24);

  // epilogue: cross-wave reduce + fbb fold + residual + store
  if (w > 0) red[w - 1][lane] = acc;
  __syncthreads();
  if (w == 0) {
#pragma unroll
    for (int j = 0; j < 3; ++j) {
      float4 r4 = red[j][lane];
      acc.x += r4.x; acc.y += r4.y; acc.z += r4.z; acc.w += r4.w;
    }
    float4 fbn = fbb[(size_t)n * 64 + lane];
    float4 bb = ((const float4*)fbbred)[lane];
    float4 o;
    o.x = fbn.x + acc.x + lmn * bb.x;
    o.y = fbn.y + acc.y + lmn * bb.y;
    o.z = fbn.z + acc.z + lmn * bb.z;
    o.w = fbn.w + acc.w + lmn * bb.w;
    ((float4*)out)[(size_t)bn * 64 + lane] = o;
  }
}

extern "C" void kernel_launch(void* const* d_in, const int* in_sizes, int n_in,
                              void* d_out, int out_size, void* d_ws, size_t ws_size,
                              hipStream_t stream) {
  const float* f_b   = (const float*)d_in[0];
  const float* f_w   = (const float*)d_in[1];
  const float* f_s   = (const float*)d_in[2];
  const float* f_m   = (const float*)d_in[3];
  const float* qmask = (const float*)d_in[4];
  const float* lmask = (const float*)d_in[5];
  const float* Wq    = (const float*)d_in[6];
  const float* bq    = (const float*)d_in[7];
  const float* Wk    = (const float*)d_in[8];
  const float* bk    = (const float*)d_in[9];
  float* out = (float*)d_out;

  float* ws  = (float*)d_ws;
  float* k2f = ws;                          // 61440 (pad 65536)
  float* sv  = ws + 65536;                  // 240  (pad 1024)
  float* fbq = ws + 131072;                 // 262144

  hipLaunchKernelGGL(kk2, dim3(B_ * L_), dim3(256), 0, stream,
                     f_w, Wk, bk, Wq, bq, k2f, sv);
  hipLaunchKernelGGL(aw_fbq, dim3(256), dim3(256), 0, stream,
                     f_b, f_w, f_s, qmask, lmask, k2f, sv, fbq);
  hipLaunchKernelGGL(fused_stream, dim3(B_ * N_), dim3(256), 0, stream,
                     f_b, f_m, f_s, lmask, fbq, out);
}